// Round 18
// baseline (82.714 us; speedup 1.0000x reference)
//
#include <hip/hip_runtime.h>
#include <float.h>

#define BLK 256
#define NB 8
#define NPTS 8192
#define WPB 4      // waves per block
#define RPW 4      // 32-row strips (A fragments) per wave
#define CSPLIT 4   // column chunks per (batch, dir)
#define LCS 2      // log2(CSPLIT)
#define TPC (NPTS / 32 / CSPLIT)   // 64 col-tiles per chunk

typedef short bf16x8 __attribute__((ext_vector_type(8)));
typedef float f32x16 __attribute__((ext_vector_type(16)));

static __device__ __forceinline__ unsigned short f2bf(float f) {   // RNE f32->bf16
    union { float f; unsigned int u; } v; v.f = f;
    unsigned int u = v.u + 0x7FFFu + ((v.u >> 16) & 1u);
    return (unsigned short)(u >> 16);
}
static __device__ __forceinline__ float bf2f(unsigned short h) {
    union { unsigned int u; float f; } v; v.u = ((unsigned int)h) << 16;
    return v.f;
}

__global__ __launch_bounds__(BLK) void init_out(int* __restrict__ outI, int n) {
    const int i = blockIdx.x * BLK + threadIdx.x;
    if (i < n) outI[i] = 0x7F800000;   // +inf bits; atomicMin-as-int = float min (r10-r17 proven)
}

// Emit BOTH layouts for BOTH point sets (K=16 bf16 slots per point; r13/r17-verified):
//   query layout:  [qh0..2, ql0..2, qh0..2, ql0..2, 1, 1, x2h, x2l]
//   target layout: [th0..2, th0..2, tl0..2, tl0..2, wh, wl, 1, 1], t = -2y, w=||y||^2
// Sum_k A_k*B_k = ||x||^2 + ||y||^2 - 2 x.y  (bf16 products exact in f32).
__global__ __launch_bounds__(BLK) void prep_kernel(
    const float* __restrict__ xyz1, const float* __restrict__ xyz2,
    unsigned short* __restrict__ Aq1, unsigned short* __restrict__ Bt1,
    unsigned short* __restrict__ Aq2, unsigned short* __restrict__ Bt2, int npts)
{
    const int i = blockIdx.x * BLK + threadIdx.x;
    if (i >= npts) return;
    const unsigned short one = 0x3F80;
    const float* srcs[2] = { xyz1, xyz2 };
    unsigned short* aouts[2] = { Aq1, Aq2 };
    unsigned short* bouts[2] = { Bt1, Bt2 };
#pragma unroll
    for (int s = 0; s < 2; ++s) {
        const float p0 = srcs[s][3*(size_t)i], p1 = srcs[s][3*(size_t)i+1], p2 = srcs[s][3*(size_t)i+2];
        {
            const unsigned short h0 = f2bf(p0), h1 = f2bf(p1), h2 = f2bf(p2);
            const unsigned short l0 = f2bf(p0 - bf2f(h0)), l1 = f2bf(p1 - bf2f(h1)), l2 = f2bf(p2 - bf2f(h2));
            const float q2 = fmaf(p0, p0, fmaf(p1, p1, p2 * p2));
            const unsigned short q2h = f2bf(q2), q2l = f2bf(q2 - bf2f(q2h));
            unsigned short* o = aouts[s] + 16*(size_t)i;
            o[0]=h0; o[1]=h1; o[2]=h2; o[3]=l0; o[4]=l1; o[5]=l2;
            o[6]=h0; o[7]=h1; o[8]=h2; o[9]=l0; o[10]=l1; o[11]=l2;
            o[12]=one; o[13]=one; o[14]=q2h; o[15]=q2l;
        }
        {
            const float t0 = -2.f*p0, t1 = -2.f*p1, t2 = -2.f*p2;
            const unsigned short h0 = f2bf(t0), h1 = f2bf(t1), h2 = f2bf(t2);
            const unsigned short l0 = f2bf(t0 - bf2f(h0)), l1 = f2bf(t1 - bf2f(h1)), l2 = f2bf(t2 - bf2f(h2));
            const float w = fmaf(p0, p0, fmaf(p1, p1, p2 * p2));
            const unsigned short wh = f2bf(w), wl = f2bf(w - bf2f(wh));
            unsigned short* o = bouts[s] + 16*(size_t)i;
            o[0]=h0; o[1]=h1; o[2]=h2; o[3]=h0; o[4]=h1; o[5]=h2;
            o[6]=l0; o[7]=l1; o[8]=l2; o[9]=l0; o[10]=l1; o[11]=l2;
            o[12]=wh; o[13]=wl; o[14]=one; o[15]=one;
        }
    }
}

// Both chamfer directions as ROW-min MFMA passes. RPW=4 A-fragments per wave:
// each B tile-pair load feeds 8 MFMA + 128 min3 (~320 issue cyc) — covers L2
// latency with the 1-ahead prefetch and halves B traffic vs RPW=2.
__global__ __launch_bounds__(BLK) void chamfer_mfma(
    const bf16x8* __restrict__ Aq1, const bf16x8* __restrict__ Bt1,
    const bf16x8* __restrict__ Aq2, const bf16x8* __restrict__ Bt2,
    int* __restrict__ outI)
{
    const int wave  = threadIdx.x >> 6;
    const int lane  = threadIdx.x & 63;
    const int l31   = lane & 31;
    const int khalf = lane >> 5;

    const int z     = blockIdx.z;          // [0, 2*CSPLIT)
    const int dir   = z >> LCS;
    const int chunk = z & (CSPLIT - 1);
    const int batch = blockIdx.y;

    const bf16x8* __restrict__ A  = dir ? Aq2 : Aq1;
    const bf16x8* __restrict__ Bt = dir ? Bt1 : Bt2;
    int* outbase = outI + (size_t)dir * NB * NPTS + (size_t)batch * NPTS;

    const size_t pbase = (size_t)batch * NPTS;
    const int r0 = (blockIdx.x * WPB + wave) * (RPW * 32);

    bf16x8 afrag[RPW];
#pragma unroll
    for (int r = 0; r < RPW; ++r)
        afrag[r] = A[(pbase + r0 + r * 32 + l31) * 2 + khalf];

    float acc[RPW][16];
#pragma unroll
    for (int r = 0; r < RPW; ++r)
#pragma unroll
        for (int i = 0; i < 16; ++i) acc[r][i] = FLT_MAX;

    const f32x16 zero = {};
    int mcur = chunk * (NPTS / CSPLIT) + l31;   // point (col) index for this lane
    bf16x8 bA = Bt[(pbase + mcur     ) * 2 + khalf];
    bf16x8 bB = Bt[(pbase + mcur + 32) * 2 + khalf];

    for (int t = 0; t < TPC; t += 2) {          // 2 col-tiles per iteration
        const int mnext = (t + 2 < TPC) ? mcur + 64 : mcur;   // uniform clamp
        const bf16x8 nA = Bt[(pbase + mnext     ) * 2 + khalf];
        const bf16x8 nB = Bt[(pbase + mnext + 32) * 2 + khalf];

        // Interleave per-r (MFMA pair -> fold) to bound live d-tile registers.
#pragma unroll
        for (int r = 0; r < RPW; ++r) {
            const f32x16 dA = __builtin_amdgcn_mfma_f32_32x32x16_bf16(afrag[r], bA, zero, 0, 0, 0);
            const f32x16 dB = __builtin_amdgcn_mfma_f32_32x32x16_bf16(afrag[r], bB, zero, 0, 0, 0);
#pragma unroll
            for (int i = 0; i < 16; ++i) {      // rows distinct; 2 candidates/op
                const float a = dA[i], b = dB[i];
                asm("v_min3_f32 %0, %1, %2, %3" : "=v"(acc[r][i]) : "v"(a), "v"(b), "0"(acc[r][i]));
            }
        }
        bA = nA; bB = nB; mcur = mnext;
    }

    // Epilogue: butterfly min over the 32 lanes (cols) of each khalf group,
    // then lane l31==i issues one atomic per row-strip. khalf 0/1 hold
    // DIFFERENT rows (row = (i&3)+8*(i>>2)+4*khalf) — no double-writes.
#pragma unroll
    for (int i = 0; i < 16; ++i) {
        float v[RPW];
#pragma unroll
        for (int r = 0; r < RPW; ++r) v[r] = acc[r][i];
#pragma unroll
        for (int off = 1; off < 32; off <<= 1) {
#pragma unroll
            for (int r = 0; r < RPW; ++r)
                v[r] = fminf(v[r], __shfl_xor(v[r], off, 64));
        }
        if (l31 == i) {
            const int row = (i & 3) + 8 * (i >> 2) + 4 * khalf;
#pragma unroll
            for (int r = 0; r < RPW; ++r)
                atomicMin(outbase + r0 + r * 32 + row, __float_as_int(v[r]));
        }
    }
}

// Safety fallback if ws is too small.
__global__ __launch_bounds__(BLK) void chamfer_fallback(
    const float* __restrict__ xyz1, const float* __restrict__ xyz2,
    float* __restrict__ out, int B, int N, int M)
{
    const int dir = blockIdx.z;
    const int b   = blockIdx.y;
    const float* Q = (dir == 0) ? xyz1 : xyz2;
    const float* T = (dir == 0) ? xyz2 : xyz1;
    const int nQ = (dir == 0) ? N : M;
    const int nT = (dir == 0) ? M : N;
    const int i = blockIdx.x * BLK + threadIdx.x;

    float x0 = 0.f, x1 = 0.f, x2 = 0.f;
    if (i < nQ) {
        const float* q = Q + ((size_t)b * nQ + i) * 3;
        x0 = q[0]; x1 = q[1]; x2 = q[2];
    }
    float best = FLT_MAX;
    for (int jj = 0; jj < nT; ++jj) {
        const float* t = T + ((size_t)b * nT + jj) * 3;
        float t0 = t[0] - x0, t1 = t[1] - x1, t2 = t[2] - x2;
        best = fminf(best, fmaf(t0, t0, fmaf(t1, t1, t2 * t2)));
    }
    if (i < nQ) {
        const size_t off = (dir == 0) ? ((size_t)b * N + i)
                                      : ((size_t)B * N + (size_t)b * M + i);
        out[off] = best;
    }
}

extern "C" void kernel_launch(void* const* d_in, const int* in_sizes, int n_in,
                              void* d_out, int out_size, void* d_ws, size_t ws_size,
                              hipStream_t stream) {
    const float* xyz1 = (const float*)d_in[0];
    const float* xyz2 = (const float*)d_in[1];

    const int npts = NB * NPTS;                   // 65536 points per set
    const size_t buf = (size_t)npts * 32;         // 2 MB per layout buffer

    if (ws_size >= 4 * buf) {
        unsigned short* Aq1 = (unsigned short*)d_ws;
        unsigned short* Bt1 = (unsigned short*)((char*)d_ws + buf);
        unsigned short* Aq2 = (unsigned short*)((char*)d_ws + 2*buf);
        unsigned short* Bt2 = (unsigned short*)((char*)d_ws + 3*buf);
        int* outI = (int*)d_out;
        const int outn = 2 * NB * NPTS;

        init_out<<<(outn + BLK - 1) / BLK, BLK, 0, stream>>>(outI, outn);
        prep_kernel<<<(npts + BLK - 1) / BLK, BLK, 0, stream>>>(
            xyz1, xyz2, Aq1, Bt1, Aq2, Bt2, npts);

        dim3 grid(NPTS / 32 / (WPB * RPW), NB, 2 * CSPLIT);   // (16, 8, 8) = 1024 blocks
        chamfer_mfma<<<grid, dim3(BLK, 1, 1), 0, stream>>>(
            (const bf16x8*)Aq1, (const bf16x8*)Bt1,
            (const bf16x8*)Aq2, (const bf16x8*)Bt2, outI);
    } else {
        dim3 grid((NPTS + BLK - 1) / BLK, NB, 2);
        chamfer_fallback<<<grid, dim3(BLK, 1, 1), 0, stream>>>(
            xyz1, xyz2, (float*)d_out, NB, NPTS, NPTS);
    }
}

// Round 20
// 75.024 us; speedup vs baseline: 1.1025x; 1.1025x over previous
//
#include <hip/hip_runtime.h>
#include <float.h>

#define BLK 256
#define NB 8
#define NPTS 8192
#define WPB 4      // waves per block
#define RPW 2      // 32-row strips (A fragments) per wave
#define CSPLIT 4   // column chunks per (batch, dir)
#define LCS 2      // log2(CSPLIT)
#define TPC (NPTS / 32 / CSPLIT)   // 64 col-tiles per chunk

typedef short bf16x8 __attribute__((ext_vector_type(8)));
typedef float f32x16 __attribute__((ext_vector_type(16)));

static __device__ __forceinline__ unsigned short f2bf(float f) {   // RNE f32->bf16
    union { float f; unsigned int u; } v; v.f = f;
    unsigned int u = v.u + 0x7FFFu + ((v.u >> 16) & 1u);
    return (unsigned short)(u >> 16);
}
static __device__ __forceinline__ float bf2f(unsigned short h) {
    union { unsigned int u; float f; } v; v.u = ((unsigned int)h) << 16;
    return v.f;
}

__global__ __launch_bounds__(BLK) void init_out(int* __restrict__ outI, int n) {
    const int i = blockIdx.x * BLK + threadIdx.x;
    if (i < n) outI[i] = 0x7F800000;   // +inf bits; atomicMin-as-int = float min (r10-r18 proven)
}

// Emit BOTH layouts for BOTH point sets (K=16 bf16 slots per point; r13/r17-verified):
//   query layout:  [qh0..2, ql0..2, qh0..2, ql0..2, 1, 1, x2h, x2l]
//   target layout: [th0..2, th0..2, tl0..2, tl0..2, wh, wl, 1, 1], t = -2y, w=||y||^2
// Sum_k A_k*B_k = ||x||^2 + ||y||^2 - 2 x.y  (bf16 products exact in f32).
__global__ __launch_bounds__(BLK) void prep_kernel(
    const float* __restrict__ xyz1, const float* __restrict__ xyz2,
    unsigned short* __restrict__ Aq1, unsigned short* __restrict__ Bt1,
    unsigned short* __restrict__ Aq2, unsigned short* __restrict__ Bt2, int npts)
{
    const int i = blockIdx.x * BLK + threadIdx.x;
    if (i >= npts) return;
    const unsigned short one = 0x3F80;
    const float* srcs[2] = { xyz1, xyz2 };
    unsigned short* aouts[2] = { Aq1, Aq2 };
    unsigned short* bouts[2] = { Bt1, Bt2 };
#pragma unroll
    for (int s = 0; s < 2; ++s) {
        const float p0 = srcs[s][3*(size_t)i], p1 = srcs[s][3*(size_t)i+1], p2 = srcs[s][3*(size_t)i+2];
        {
            const unsigned short h0 = f2bf(p0), h1 = f2bf(p1), h2 = f2bf(p2);
            const unsigned short l0 = f2bf(p0 - bf2f(h0)), l1 = f2bf(p1 - bf2f(h1)), l2 = f2bf(p2 - bf2f(h2));
            const float q2 = fmaf(p0, p0, fmaf(p1, p1, p2 * p2));
            const unsigned short q2h = f2bf(q2), q2l = f2bf(q2 - bf2f(q2h));
            unsigned short* o = aouts[s] + 16*(size_t)i;
            o[0]=h0; o[1]=h1; o[2]=h2; o[3]=l0; o[4]=l1; o[5]=l2;
            o[6]=h0; o[7]=h1; o[8]=h2; o[9]=l0; o[10]=l1; o[11]=l2;
            o[12]=one; o[13]=one; o[14]=q2h; o[15]=q2l;
        }
        {
            const float t0 = -2.f*p0, t1 = -2.f*p1, t2 = -2.f*p2;
            const unsigned short h0 = f2bf(t0), h1 = f2bf(t1), h2 = f2bf(t2);
            const unsigned short l0 = f2bf(t0 - bf2f(h0)), l1 = f2bf(t1 - bf2f(h1)), l2 = f2bf(t2 - bf2f(h2));
            const float w = fmaf(p0, p0, fmaf(p1, p1, p2 * p2));
            const unsigned short wh = f2bf(w), wl = f2bf(w - bf2f(wh));
            unsigned short* o = bouts[s] + 16*(size_t)i;
            o[0]=h0; o[1]=h1; o[2]=h2; o[3]=h0; o[4]=h1; o[5]=h2;
            o[6]=l0; o[7]=l1; o[8]=l2; o[9]=l0; o[10]=l1; o[11]=l2;
            o[12]=wh; o[13]=wl; o[14]=one; o[15]=one;
        }
    }
}

// Row-min MFMA passes, 4-tile B groups: 4 independent prefetch loads (4 KB/wave)
// in flight while ~200 cyc of MFMA+fold executes. CSPLIT=4 -> 2048 blocks for
// occupancy. Fold: t=min3(dA,dB,dC); acc=min3(t,dD,acc) — 2 min3 per 4 tiles.
__global__ __launch_bounds__(BLK) void chamfer_mfma(
    const bf16x8* __restrict__ Aq1, const bf16x8* __restrict__ Bt1,
    const bf16x8* __restrict__ Aq2, const bf16x8* __restrict__ Bt2,
    int* __restrict__ outI)
{
    const int wave  = threadIdx.x >> 6;
    const int lane  = threadIdx.x & 63;
    const int l31   = lane & 31;
    const int khalf = lane >> 5;

    const int z     = blockIdx.z;          // [0, 2*CSPLIT)
    const int dir   = z >> LCS;
    const int chunk = z & (CSPLIT - 1);
    const int batch = blockIdx.y;

    const bf16x8* __restrict__ A  = dir ? Aq2 : Aq1;
    const bf16x8* __restrict__ Bt = dir ? Bt1 : Bt2;
    int* outbase = outI + (size_t)dir * NB * NPTS + (size_t)batch * NPTS;

    const size_t pbase = (size_t)batch * NPTS;
    const int r0 = (blockIdx.x * WPB + wave) * (RPW * 32);

    bf16x8 afrag[RPW];
#pragma unroll
    for (int r = 0; r < RPW; ++r)
        afrag[r] = A[(pbase + r0 + r * 32 + l31) * 2 + khalf];

    float acc[RPW][16];
#pragma unroll
    for (int r = 0; r < RPW; ++r)
#pragma unroll
        for (int i = 0; i < 16; ++i) acc[r][i] = FLT_MAX;

    const f32x16 zero = {};
    int mcur = chunk * (NPTS / CSPLIT) + l31;   // point (col) index for this lane
    bf16x8 c0 = Bt[(pbase + mcur     ) * 2 + khalf];
    bf16x8 c1 = Bt[(pbase + mcur + 32) * 2 + khalf];
    bf16x8 c2 = Bt[(pbase + mcur + 64) * 2 + khalf];
    bf16x8 c3 = Bt[(pbase + mcur + 96) * 2 + khalf];

    for (int t = 0; t < TPC; t += 4) {          // 4 col-tiles per iteration (16 iters)
        const int mnext = (t + 4 < TPC) ? mcur + 128 : mcur;   // uniform clamp
        const bf16x8 n0 = Bt[(pbase + mnext     ) * 2 + khalf];
        const bf16x8 n1 = Bt[(pbase + mnext + 32) * 2 + khalf];
        const bf16x8 n2 = Bt[(pbase + mnext + 64) * 2 + khalf];
        const bf16x8 n3 = Bt[(pbase + mnext + 96) * 2 + khalf];

#pragma unroll
        for (int r = 0; r < RPW; ++r) {
            const f32x16 dA = __builtin_amdgcn_mfma_f32_32x32x16_bf16(afrag[r], c0, zero, 0, 0, 0);
            const f32x16 dB = __builtin_amdgcn_mfma_f32_32x32x16_bf16(afrag[r], c1, zero, 0, 0, 0);
            const f32x16 dC = __builtin_amdgcn_mfma_f32_32x32x16_bf16(afrag[r], c2, zero, 0, 0, 0);
            const f32x16 dD = __builtin_amdgcn_mfma_f32_32x32x16_bf16(afrag[r], c3, zero, 0, 0, 0);
#pragma unroll
            for (int i = 0; i < 16; ++i) {      // rows distinct; 4 candidates / 2 min3
                const float a = dA[i], b = dB[i], c = dC[i], d = dD[i];
                float t0;
                asm("v_min3_f32 %0, %1, %2, %3" : "=v"(t0) : "v"(a), "v"(b), "v"(c));
                asm("v_min3_f32 %0, %1, %2, %3" : "=v"(acc[r][i]) : "v"(t0), "v"(d), "0"(acc[r][i]));
            }
        }
        c0 = n0; c1 = n1; c2 = n2; c3 = n3; mcur = mnext;
    }

    // Epilogue: butterfly min over the 32 lanes (cols) of each khalf group,
    // then lane l31==i issues one atomic per row-strip. khalf 0/1 hold
    // DIFFERENT rows (row = (i&3)+8*(i>>2)+4*khalf) — no double-writes.
#pragma unroll
    for (int i = 0; i < 16; ++i) {
        float v[RPW];
#pragma unroll
        for (int r = 0; r < RPW; ++r) v[r] = acc[r][i];
#pragma unroll
        for (int off = 1; off < 32; off <<= 1) {
#pragma unroll
            for (int r = 0; r < RPW; ++r)
                v[r] = fminf(v[r], __shfl_xor(v[r], off, 64));
        }
        if (l31 == i) {
            const int row = (i & 3) + 8 * (i >> 2) + 4 * khalf;
#pragma unroll
            for (int r = 0; r < RPW; ++r)
                atomicMin(outbase + r0 + r * 32 + row, __float_as_int(v[r]));
        }
    }
}

// Safety fallback if ws is too small.
__global__ __launch_bounds__(BLK) void chamfer_fallback(
    const float* __restrict__ xyz1, const float* __restrict__ xyz2,
    float* __restrict__ out, int B, int N, int M)
{
    const int dir = blockIdx.z;
    const int b   = blockIdx.y;
    const float* Q = (dir == 0) ? xyz1 : xyz2;
    const float* T = (dir == 0) ? xyz2 : xyz1;
    const int nQ = (dir == 0) ? N : M;
    const int nT = (dir == 0) ? M : N;
    const int i = blockIdx.x * BLK + threadIdx.x;

    float x0 = 0.f, x1 = 0.f, x2 = 0.f;
    if (i < nQ) {
        const float* q = Q + ((size_t)b * nQ + i) * 3;
        x0 = q[0]; x1 = q[1]; x2 = q[2];
    }
    float best = FLT_MAX;
    for (int jj = 0; jj < nT; ++jj) {
        const float* t = T + ((size_t)b * nT + jj) * 3;
        float t0 = t[0] - x0, t1 = t[1] - x1, t2 = t[2] - x2;
        best = fminf(best, fmaf(t0, t0, fmaf(t1, t1, t2 * t2)));
    }
    if (i < nQ) {
        const size_t off = (dir == 0) ? ((size_t)b * N + i)
                                      : ((size_t)B * N + (size_t)b * M + i);
        out[off] = best;
    }
}

extern "C" void kernel_launch(void* const* d_in, const int* in_sizes, int n_in,
                              void* d_out, int out_size, void* d_ws, size_t ws_size,
                              hipStream_t stream) {
    const float* xyz1 = (const float*)d_in[0];
    const float* xyz2 = (const float*)d_in[1];

    const int npts = NB * NPTS;                   // 65536 points per set
    const size_t buf = (size_t)npts * 32;         // 2 MB per layout buffer

    if (ws_size >= 4 * buf) {
        unsigned short* Aq1 = (unsigned short*)d_ws;
        unsigned short* Bt1 = (unsigned short*)((char*)d_ws + buf);
        unsigned short* Aq2 = (unsigned short*)((char*)d_ws + 2*buf);
        unsigned short* Bt2 = (unsigned short*)((char*)d_ws + 3*buf);
        int* outI = (int*)d_out;
        const int outn = 2 * NB * NPTS;

        init_out<<<(outn + BLK - 1) / BLK, BLK, 0, stream>>>(outI, outn);
        prep_kernel<<<(npts + BLK - 1) / BLK, BLK, 0, stream>>>(
            xyz1, xyz2, Aq1, Bt1, Aq2, Bt2, npts);

        dim3 grid(NPTS / 32 / (WPB * RPW), NB, 2 * CSPLIT);   // (32, 8, 8) = 2048 blocks
        chamfer_mfma<<<grid, dim3(BLK, 1, 1), 0, stream>>>(
            (const bf16x8*)Aq1, (const bf16x8*)Bt1,
            (const bf16x8*)Aq2, (const bf16x8*)Bt2, outI);
    } else {
        dim3 grid((NPTS + BLK - 1) / BLK, NB, 2);
        chamfer_fallback<<<grid, dim3(BLK, 1, 1), 0, stream>>>(
            xyz1, xyz2, (float*)d_out, NB, NPTS, NPTS);
    }
}

// Round 21
// 66.719 us; speedup vs baseline: 1.2397x; 1.1245x over previous
//
#include <hip/hip_runtime.h>
#include <float.h>

#define BLK 256
#define NB 8
#define NPTS 8192
#define WPB 4      // waves per block
#define RPW 2      // 32-row strips (A fragments) per wave
#define CSPLIT 4   // column chunks per (batch, dir)
#define LCS 2      // log2(CSPLIT)
#define TPC (NPTS / 32 / CSPLIT)   // 64 col-tiles per chunk

typedef short bf16x8 __attribute__((ext_vector_type(8)));
typedef float f32x16 __attribute__((ext_vector_type(16)));

static __device__ __forceinline__ unsigned short f2bf(float f) {   // RNE f32->bf16
    union { float f; unsigned int u; } v; v.f = f;
    unsigned int u = v.u + 0x7FFFu + ((v.u >> 16) & 1u);
    return (unsigned short)(u >> 16);
}
static __device__ __forceinline__ float bf2f(unsigned short h) {
    union { unsigned int u; float f; } v; v.u = ((unsigned int)h) << 16;
    return v.f;
}

__global__ __launch_bounds__(BLK) void init_out(int* __restrict__ outI, int n) {
    const int i = blockIdx.x * BLK + threadIdx.x;
    if (i < n) outI[i] = 0x7F800000;   // +inf bits; atomicMin-as-int = float min (r10-r20 proven)
}

// Emit BOTH layouts for BOTH point sets (K=16 bf16 slots per point; r13/r17-verified):
//   query layout:  [qh0..2, ql0..2, qh0..2, ql0..2, 1, 1, x2h, x2l]
//   target layout: [th0..2, th0..2, tl0..2, tl0..2, wh, wl, 1, 1], t = -2y, w=||y||^2
// Sum_k A_k*B_k = ||x||^2 + ||y||^2 - 2 x.y  (bf16 products exact in f32).
__global__ __launch_bounds__(BLK) void prep_kernel(
    const float* __restrict__ xyz1, const float* __restrict__ xyz2,
    unsigned short* __restrict__ Aq1, unsigned short* __restrict__ Bt1,
    unsigned short* __restrict__ Aq2, unsigned short* __restrict__ Bt2, int npts)
{
    const int i = blockIdx.x * BLK + threadIdx.x;
    if (i >= npts) return;
    const unsigned short one = 0x3F80;
    const float* srcs[2] = { xyz1, xyz2 };
    unsigned short* aouts[2] = { Aq1, Aq2 };
    unsigned short* bouts[2] = { Bt1, Bt2 };
#pragma unroll
    for (int s = 0; s < 2; ++s) {
        const float p0 = srcs[s][3*(size_t)i], p1 = srcs[s][3*(size_t)i+1], p2 = srcs[s][3*(size_t)i+2];
        {
            const unsigned short h0 = f2bf(p0), h1 = f2bf(p1), h2 = f2bf(p2);
            const unsigned short l0 = f2bf(p0 - bf2f(h0)), l1 = f2bf(p1 - bf2f(h1)), l2 = f2bf(p2 - bf2f(h2));
            const float q2 = fmaf(p0, p0, fmaf(p1, p1, p2 * p2));
            const unsigned short q2h = f2bf(q2), q2l = f2bf(q2 - bf2f(q2h));
            unsigned short* o = aouts[s] + 16*(size_t)i;
            o[0]=h0; o[1]=h1; o[2]=h2; o[3]=l0; o[4]=l1; o[5]=l2;
            o[6]=h0; o[7]=h1; o[8]=h2; o[9]=l0; o[10]=l1; o[11]=l2;
            o[12]=one; o[13]=one; o[14]=q2h; o[15]=q2l;
        }
        {
            const float t0 = -2.f*p0, t1 = -2.f*p1, t2 = -2.f*p2;
            const unsigned short h0 = f2bf(t0), h1 = f2bf(t1), h2 = f2bf(t2);
            const unsigned short l0 = f2bf(t0 - bf2f(h0)), l1 = f2bf(t1 - bf2f(h1)), l2 = f2bf(t2 - bf2f(h2));
            const float w = fmaf(p0, p0, fmaf(p1, p1, p2 * p2));
            const unsigned short wh = f2bf(w), wl = f2bf(w - bf2f(wh));
            unsigned short* o = bouts[s] + 16*(size_t)i;
            o[0]=h0; o[1]=h1; o[2]=h2; o[3]=h0; o[4]=h1; o[5]=h2;
            o[6]=l0; o[7]=l1; o[8]=l2; o[9]=l0; o[10]=l1; o[11]=l2;
            o[12]=wh; o[13]=wl; o[14]=one; o[15]=one;
        }
    }
}

// Row-min MFMA passes. KEY CHANGE vs r20: no inline-asm min3 (its "v"
// constraints forced v_accvgpr_read floods when MFMA results landed in
// AGPRs under the default register budget). fminf chains let the backend
// fuse to v_min3_f32 and read results in place; __launch_bounds__(BLK,2)
// gives a 256-VGPR budget so results stay in VGPRs.
__global__ __launch_bounds__(BLK, 2) void chamfer_mfma(
    const bf16x8* __restrict__ Aq1, const bf16x8* __restrict__ Bt1,
    const bf16x8* __restrict__ Aq2, const bf16x8* __restrict__ Bt2,
    int* __restrict__ outI)
{
    const int wave  = threadIdx.x >> 6;
    const int lane  = threadIdx.x & 63;
    const int l31   = lane & 31;
    const int khalf = lane >> 5;

    const int z     = blockIdx.z;          // [0, 2*CSPLIT)
    const int dir   = z >> LCS;
    const int chunk = z & (CSPLIT - 1);
    const int batch = blockIdx.y;

    const bf16x8* __restrict__ A  = dir ? Aq2 : Aq1;
    const bf16x8* __restrict__ Bt = dir ? Bt1 : Bt2;
    int* outbase = outI + (size_t)dir * NB * NPTS + (size_t)batch * NPTS;

    const size_t pbase = (size_t)batch * NPTS;
    const int r0 = (blockIdx.x * WPB + wave) * (RPW * 32);

    bf16x8 afrag[RPW];
#pragma unroll
    for (int r = 0; r < RPW; ++r)
        afrag[r] = A[(pbase + r0 + r * 32 + l31) * 2 + khalf];

    float acc[RPW][16];
#pragma unroll
    for (int r = 0; r < RPW; ++r)
#pragma unroll
        for (int i = 0; i < 16; ++i) acc[r][i] = FLT_MAX;

    const f32x16 zero = {};
    int mcur = chunk * (NPTS / CSPLIT) + l31;   // point (col) index for this lane
    bf16x8 c0 = Bt[(pbase + mcur     ) * 2 + khalf];
    bf16x8 c1 = Bt[(pbase + mcur + 32) * 2 + khalf];
    bf16x8 c2 = Bt[(pbase + mcur + 64) * 2 + khalf];
    bf16x8 c3 = Bt[(pbase + mcur + 96) * 2 + khalf];

    for (int t = 0; t < TPC; t += 4) {          // 4 col-tiles per iteration (16 iters)
        const int mnext = (t + 4 < TPC) ? mcur + 128 : mcur;   // uniform clamp
        const bf16x8 n0 = Bt[(pbase + mnext     ) * 2 + khalf];
        const bf16x8 n1 = Bt[(pbase + mnext + 32) * 2 + khalf];
        const bf16x8 n2 = Bt[(pbase + mnext + 64) * 2 + khalf];
        const bf16x8 n3 = Bt[(pbase + mnext + 96) * 2 + khalf];

#pragma unroll
        for (int r = 0; r < RPW; ++r) {
            const f32x16 dA = __builtin_amdgcn_mfma_f32_32x32x16_bf16(afrag[r], c0, zero, 0, 0, 0);
            const f32x16 dB = __builtin_amdgcn_mfma_f32_32x32x16_bf16(afrag[r], c1, zero, 0, 0, 0);
            const f32x16 dC = __builtin_amdgcn_mfma_f32_32x32x16_bf16(afrag[r], c2, zero, 0, 0, 0);
            const f32x16 dD = __builtin_amdgcn_mfma_f32_32x32x16_bf16(afrag[r], c3, zero, 0, 0, 0);
#pragma unroll
            for (int i = 0; i < 16; ++i) {      // 2 fused min3 per elem per 4 tiles
                const float m1 = fminf(fminf(dA[i], dB[i]), dC[i]);
                acc[r][i] = fminf(fminf(m1, dD[i]), acc[r][i]);
            }
        }
        c0 = n0; c1 = n1; c2 = n2; c3 = n3; mcur = mnext;
    }

    // Epilogue: butterfly min over the 32 lanes (cols) of each khalf group,
    // then lane l31==i issues one atomic per row-strip. khalf 0/1 hold
    // DIFFERENT rows (row = (i&3)+8*(i>>2)+4*khalf) — no double-writes.
#pragma unroll
    for (int i = 0; i < 16; ++i) {
        float v[RPW];
#pragma unroll
        for (int r = 0; r < RPW; ++r) v[r] = acc[r][i];
#pragma unroll
        for (int off = 1; off < 32; off <<= 1) {
#pragma unroll
            for (int r = 0; r < RPW; ++r)
                v[r] = fminf(v[r], __shfl_xor(v[r], off, 64));
        }
        if (l31 == i) {
            const int row = (i & 3) + 8 * (i >> 2) + 4 * khalf;
#pragma unroll
            for (int r = 0; r < RPW; ++r)
                atomicMin(outbase + r0 + r * 32 + row, __float_as_int(v[r]));
        }
    }
}

// Safety fallback if ws is too small.
__global__ __launch_bounds__(BLK) void chamfer_fallback(
    const float* __restrict__ xyz1, const float* __restrict__ xyz2,
    float* __restrict__ out, int B, int N, int M)
{
    const int dir = blockIdx.z;
    const int b   = blockIdx.y;
    const float* Q = (dir == 0) ? xyz1 : xyz2;
    const float* T = (dir == 0) ? xyz2 : xyz1;
    const int nQ = (dir == 0) ? N : M;
    const int nT = (dir == 0) ? M : N;
    const int i = blockIdx.x * BLK + threadIdx.x;

    float x0 = 0.f, x1 = 0.f, x2 = 0.f;
    if (i < nQ) {
        const float* q = Q + ((size_t)b * nQ + i) * 3;
        x0 = q[0]; x1 = q[1]; x2 = q[2];
    }
    float best = FLT_MAX;
    for (int jj = 0; jj < nT; ++jj) {
        const float* t = T + ((size_t)b * nT + jj) * 3;
        float t0 = t[0] - x0, t1 = t[1] - x1, t2 = t[2] - x2;
        best = fminf(best, fmaf(t0, t0, fmaf(t1, t1, t2 * t2)));
    }
    if (i < nQ) {
        const size_t off = (dir == 0) ? ((size_t)b * N + i)
                                      : ((size_t)B * N + (size_t)b * M + i);
        out[off] = best;
    }
}

extern "C" void kernel_launch(void* const* d_in, const int* in_sizes, int n_in,
                              void* d_out, int out_size, void* d_ws, size_t ws_size,
                              hipStream_t stream) {
    const float* xyz1 = (const float*)d_in[0];
    const float* xyz2 = (const float*)d_in[1];

    const int npts = NB * NPTS;                   // 65536 points per set
    const size_t buf = (size_t)npts * 32;         // 2 MB per layout buffer

    if (ws_size >= 4 * buf) {
        unsigned short* Aq1 = (unsigned short*)d_ws;
        unsigned short* Bt1 = (unsigned short*)((char*)d_ws + buf);
        unsigned short* Aq2 = (unsigned short*)((char*)d_ws + 2*buf);
        unsigned short* Bt2 = (unsigned short*)((char*)d_ws + 3*buf);
        int* outI = (int*)d_out;
        const int outn = 2 * NB * NPTS;

        init_out<<<(outn + BLK - 1) / BLK, BLK, 0, stream>>>(outI, outn);
        prep_kernel<<<(npts + BLK - 1) / BLK, BLK, 0, stream>>>(
            xyz1, xyz2, Aq1, Bt1, Aq2, Bt2, npts);

        dim3 grid(NPTS / 32 / (WPB * RPW), NB, 2 * CSPLIT);   // (32, 8, 8) = 2048 blocks
        chamfer_mfma<<<grid, dim3(BLK, 1, 1), 0, stream>>>(
            (const bf16x8*)Aq1, (const bf16x8*)Bt1,
            (const bf16x8*)Aq2, (const bf16x8*)Bt2, outI);
    } else {
        dim3 grid((NPTS + BLK - 1) / BLK, NB, 2);
        chamfer_fallback<<<grid, dim3(BLK, 1, 1), 0, stream>>>(
            xyz1, xyz2, (float*)d_out, NB, NPTS, NPTS);
    }
}